// Round 3
// baseline (39444.681 us; speedup 1.0000x reference)
//
#include <hip/hip_runtime.h>
#include <hip/hip_bf16.h>

#define HID 512
#define NSEQ 256
#define SLEN 512
#define VOC 32
#define SOS_TOK 0

typedef __attribute__((ext_vector_type(8))) short short8;
typedef __attribute__((ext_vector_type(4))) float f32x4;

static __device__ __forceinline__ short f2bf(float f) {
    unsigned u = __builtin_bit_cast(unsigned, f);
    unsigned r = (u + 0x7fffu + ((u >> 16) & 1u)) >> 16;
    return (short)r;
}

// ---------------- G tables: G = (relu?)(emb) @ W_ih^T + b_ih, [32 tok][1536] ----------------
__global__ void build_tables(const float* __restrict__ emb_enc, const float* __restrict__ wih_e,
                             const float* __restrict__ bih_e,
                             const float* __restrict__ emb_dec, const float* __restrict__ wih_d,
                             const float* __restrict__ bih_d,
                             float* __restrict__ genc, float* __restrict__ gdec) {
    int gid = blockIdx.x * blockDim.x + threadIdx.x;
    if (gid >= 2 * 32 * 1536) return;
    int which = gid >= 49152;
    int r = gid - which * 49152;
    int tok = r / 1536, n = r - tok * 1536;
    const float4* e = (const float4*)((which ? emb_dec : emb_enc) + tok * HID);
    const float4* w = (const float4*)((which ? wih_d : wih_e) + n * HID);
    float s = 0.f;
#pragma unroll 4
    for (int k = 0; k < 128; ++k) {
        float4 ev = e[k], wv = w[k];
        if (which) {
            ev.x = fmaxf(ev.x, 0.f); ev.y = fmaxf(ev.y, 0.f);
            ev.z = fmaxf(ev.z, 0.f); ev.w = fmaxf(ev.w, 0.f);
        }
        s += ev.x * wv.x + ev.y * wv.y + ev.z * wv.z + ev.w * wv.w;
    }
    s += which ? bih_d[n] : bih_e[n];
    (which ? gdec : genc)[r] = s;
}

struct KParams {
    const int* tokens;
    const float* whh_e; const float* bhh_e;
    const float* whh_d; const float* bhh_d;
    const float* wout;  const float* bout;
    const float* genc;  const float* gdec;
    short* hb0; short* hb1;     // bf16 h ping-pong
    float* hf0; float* hf1;     // f32 master h ping-pong
    unsigned* bar;              // 8 groups x {cnt @ mi*32, gen @ mi*32+16}
    float* out;                 // [512] embeds + [1] loss
};

// sense-reversing barrier over the 32 blocks of one mi-group
static __device__ __forceinline__ void group_barrier(unsigned* cnt, unsigned* gen) {
    __syncthreads();
    if (threadIdx.x == 0) {
        __threadfence();
        unsigned g = __hip_atomic_load(gen, __ATOMIC_SEQ_CST, __HIP_MEMORY_SCOPE_AGENT);
        unsigned old = __hip_atomic_fetch_add(cnt, 1u, __ATOMIC_SEQ_CST, __HIP_MEMORY_SCOPE_AGENT);
        if (old == 31u) {
            __hip_atomic_store(cnt, 0u, __ATOMIC_SEQ_CST, __HIP_MEMORY_SCOPE_AGENT);
            __hip_atomic_store(gen, g + 1u, __ATOMIC_SEQ_CST, __HIP_MEMORY_SCOPE_AGENT);
        } else {
            while (__hip_atomic_load(gen, __ATOMIC_SEQ_CST, __HIP_MEMORY_SCOPE_AGENT) == g)
                __builtin_amdgcn_s_sleep(1);
        }
        __threadfence();
    }
    __syncthreads();
}

__global__ __launch_bounds__(256, 1) void gru_seq(KParams p) {
    const int tid = threadIdx.x;
    const int lane = tid & 63;
    const int wave = tid >> 6;
    const int mf = wave >> 1;       // row sub-tile 0..1
    const int kh = wave & 1;        // K half 0..1
    const int mi = blockIdx.x >> 5; // batch group 0..7
    const int hj = blockIdx.x & 31; // hidden col block 0..31

    __shared__ __align__(16) short Wp[48 * 512];    // swizzled [n][k] bf16
    __shared__ __align__(16) short WoutL[32 * 512]; // swizzled [v][k] bf16
    __shared__ float GencL[32 * 48];
    __shared__ float GdecL[32 * 48];
    __shared__ float bhhL[48];
    __shared__ float boutL[32];
    __shared__ float redbuf[2][3][16][16];
    __shared__ float hredbuf[2][2][16][16];
    __shared__ float logitsL[32][33];
    __shared__ int tokL[32];

    // ---------------- setup ----------------
    for (int i = tid; i < 32 * 48; i += 256) {
        int tok = i / 48, c = i - tok * 48;
        int gcol = (c >> 4) * HID + hj * 16 + (c & 15);
        GencL[i] = p.genc[tok * 1536 + gcol];
        GdecL[i] = p.gdec[tok * 1536 + gcol];
    }
    if (hj == 0) {
        for (int i = tid; i < 32 * 512; i += 256) {
            int v = i >> 9, k = i & 511;
            WoutL[v * 512 + (((k >> 3) ^ (v & 7)) << 3) + (k & 7)] = f2bf(p.wout[v * 512 + k]);
        }
        if (tid < 32) boutL[tid] = p.bout[tid];
    }
    auto load_panel = [&](const float* whh, const float* bhh) {
        for (int i = tid; i < 48 * 512; i += 256) {
            int rowl = i >> 9, k = i & 511;
            int nrow = (rowl >> 4) * HID + hj * 16 + (rowl & 15);
            Wp[rowl * 512 + (((k >> 3) ^ (rowl & 7)) << 3) + (k & 7)] = f2bf(whh[nrow * HID + k]);
        }
        if (tid < 48) bhhL[tid] = bhh[(tid >> 4) * HID + hj * 16 + (tid & 15)];
    };
    load_panel(p.whh_e, p.bhh_e);
    __syncthreads();

    float loss_acc = 0.f;
    const int arow_l = mf * 16 + (lane & 15); // local row 0..31
    const int row_g = mi * 32 + arow_l;
    const int koff = (lane >> 4) * 8;

    unsigned* cnt = p.bar + mi * 32;
    unsigned* gen = p.bar + mi * 32 + 16;

    for (int phase = 0; phase < 2; ++phase) {
        const float* G = phase ? GdecL : GencL;
        const int nsteps = phase ? (SLEN + 1) : SLEN;
        for (int t = 0; t < nsteps; ++t) {
            const int gstep = phase * SLEN + t;
            const short* hc = (gstep & 1) ? p.hb1 : p.hb0;
            short* hn = (gstep & 1) ? p.hb0 : p.hb1;
            const float* hfc = (gstep & 1) ? p.hf1 : p.hf0;
            float* hfn = (gstep & 1) ? p.hf0 : p.hf1;
            const bool do_gru = (t < SLEN);
            const bool do_head = (phase == 1) && (t >= 1) && (hj == 0);

            int my_tgt = 0;
            if (tid < 32) {
                int rg = mi * 32 + tid;
                int tk = SOS_TOK;
                if (phase == 0) tk = p.tokens[rg * SLEN + t];
                else if (t >= 1 && t < SLEN) tk = p.tokens[rg * SLEN + t - 1];
                tokL[tid] = tk;
                if (do_head) my_tgt = p.tokens[rg * SLEN + (t - 1)];
            }

            short8 a[8];
            if (do_gru || do_head) {
                const short* ab = hc + row_g * HID + kh * 256 + koff;
#pragma unroll
                for (int kk = 0; kk < 8; ++kk) a[kk] = *(const short8*)(ab + kk * 32);
            }

            f32x4 acc0 = {0.f, 0.f, 0.f, 0.f};
            f32x4 acc1 = {0.f, 0.f, 0.f, 0.f};
            f32x4 acc2 = {0.f, 0.f, 0.f, 0.f};
            if (do_gru) {
#pragma unroll
                for (int kk = 0; kk < 8; ++kk) {
                    const int ch = (kh * 8 + kk) * 4 + (lane >> 4); // 16B chunk idx 0..63
                    {
                        const int br = lane & 15;
                        short8 b = *(const short8*)(Wp + br * 512 + ((ch ^ (br & 7)) << 3));
                        acc0 = __builtin_amdgcn_mfma_f32_16x16x32_bf16(a[kk], b, acc0, 0, 0, 0);
                    }
                    {
                        const int br = 16 + (lane & 15);
                        short8 b = *(const short8*)(Wp + br * 512 + ((ch ^ (br & 7)) << 3));
                        acc1 = __builtin_amdgcn_mfma_f32_16x16x32_bf16(a[kk], b, acc1, 0, 0, 0);
                    }
                    {
                        const int br = 32 + (lane & 15);
                        short8 b = *(const short8*)(Wp + br * 512 + ((ch ^ (br & 7)) << 3));
                        acc2 = __builtin_amdgcn_mfma_f32_16x16x32_bf16(a[kk], b, acc2, 0, 0, 0);
                    }
                }
            }
            f32x4 ha0 = {0.f, 0.f, 0.f, 0.f};
            f32x4 ha1 = {0.f, 0.f, 0.f, 0.f};
            if (do_head) {
#pragma unroll
                for (int kk = 0; kk < 8; ++kk) {
                    const int ch = (kh * 8 + kk) * 4 + (lane >> 4);
                    {
                        const int br = lane & 15;
                        short8 b = *(const short8*)(WoutL + br * 512 + ((ch ^ (br & 7)) << 3));
                        ha0 = __builtin_amdgcn_mfma_f32_16x16x32_bf16(a[kk], b, ha0, 0, 0, 0);
                    }
                    {
                        const int br = 16 + (lane & 15);
                        short8 b = *(const short8*)(WoutL + br * 512 + ((ch ^ (br & 7)) << 3));
                        ha1 = __builtin_amdgcn_mfma_f32_16x16x32_bf16(a[kk], b, ha1, 0, 0, 0);
                    }
                }
            }

            if (kh == 1) {
                if (do_gru) {
#pragma unroll
                    for (int j = 0; j < 4; ++j) {
                        int r = (lane >> 4) * 4 + j, c = lane & 15;
                        redbuf[mf][0][r][c] = acc0[j];
                        redbuf[mf][1][r][c] = acc1[j];
                        redbuf[mf][2][r][c] = acc2[j];
                    }
                }
                if (do_head) {
#pragma unroll
                    for (int j = 0; j < 4; ++j) {
                        int r = (lane >> 4) * 4 + j, c = lane & 15;
                        hredbuf[mf][0][r][c] = ha0[j];
                        hredbuf[mf][1][r][c] = ha1[j];
                    }
                }
            }
            __syncthreads();
            if (kh == 0) {
                if (do_gru) {
                    float hv[4];
#pragma unroll
                    for (int j = 0; j < 4; ++j) {
                        int r = (lane >> 4) * 4 + j;
                        int c = lane & 15;
                        int rl = mf * 16 + r;
                        float ghr = acc0[j] + redbuf[mf][0][r][c] + bhhL[c];
                        float ghz = acc1[j] + redbuf[mf][1][r][c] + bhhL[16 + c];
                        float ghn = acc2[j] + redbuf[mf][2][r][c] + bhhL[32 + c];
                        int tk = tokL[rl];
                        float gxr = G[tk * 48 + c];
                        float gxz = G[tk * 48 + 16 + c];
                        float gxn = G[tk * 48 + 32 + c];
                        float rg_ = 1.f / (1.f + __expf(-(gxr + ghr)));
                        float zg_ = 1.f / (1.f + __expf(-(gxz + ghz)));
                        float pre = gxn + rg_ * ghn;
                        float e2 = __expf(2.f * pre);
                        float ng_ = 1.f - 2.f / (e2 + 1.f);
                        int rgl = mi * 32 + rl;
                        float hold = hfc[rgl * HID + hj * 16 + c];
                        float hnew = (1.f - zg_) * ng_ + zg_ * hold;
                        hfn[rgl * HID + hj * 16 + c] = hnew;
                        hn[rgl * HID + hj * 16 + c] = f2bf(hnew);
                        hv[j] = hnew;
                    }
                    if (phase == 0 && t == SLEN - 1) {
                        float s = hv[0] + hv[1] + hv[2] + hv[3];
                        s += __shfl_xor(s, 16);
                        s += __shfl_xor(s, 32);
                        if (lane < 16) atomicAdd(p.out + hj * 16 + lane, s * (1.f / 256.f));
                    }
                }
                if (do_head) {
#pragma unroll
                    for (int j = 0; j < 4; ++j) {
                        int r = (lane >> 4) * 4 + j, c = lane & 15;
                        logitsL[mf * 16 + r][c] = ha0[j] + hredbuf[mf][0][r][c] + boutL[c];
                        logitsL[mf * 16 + r][16 + c] = ha1[j] + hredbuf[mf][1][r][c] + boutL[16 + c];
                    }
                }
            }
            if (do_head) {
                __syncthreads();
                if (tid < 32) {
                    float mx = -1e30f;
#pragma unroll
                    for (int v = 0; v < VOC; ++v) mx = fmaxf(mx, logitsL[tid][v]);
                    float se = 0.f;
#pragma unroll
                    for (int v = 0; v < VOC; ++v) se += __expf(logitsL[tid][v] - mx);
                    loss_acc += mx + __logf(se) - logitsL[tid][my_tgt];
                }
            }
            group_barrier(cnt, gen);
        }
        if (phase == 0) {
            load_panel(p.whh_d, p.bhh_d);
            __syncthreads();
        }
    }

    if (hj == 0 && wave == 0) {
        float v = loss_acc; // nonzero only in lanes 0..31
#pragma unroll
        for (int off = 32; off >= 1; off >>= 1) v += __shfl_xor(v, off);
        if (lane == 0) atomicAdd(p.out + HID, v * (1.f / (256.f * 512.f)));
    }
}

extern "C" void kernel_launch(void* const* d_in, const int* in_sizes, int n_in,
                              void* d_out, int out_size, void* d_ws, size_t ws_size,
                              hipStream_t stream) {
    const int* tokens = (const int*)d_in[0];
    const float* emb_enc = (const float*)d_in[1];
    const float* wih_e = (const float*)d_in[2];
    const float* whh_e = (const float*)d_in[3];
    const float* bih_e = (const float*)d_in[4];
    const float* bhh_e = (const float*)d_in[5];
    const float* emb_dec = (const float*)d_in[6];
    const float* wih_d = (const float*)d_in[7];
    const float* whh_d = (const float*)d_in[8];
    const float* bih_d = (const float*)d_in[9];
    const float* bhh_d = (const float*)d_in[10];
    const float* wout = (const float*)d_in[11];
    const float* bout = (const float*)d_in[12];

    char* ws = (char*)d_ws;
    short* hb0 = (short*)(ws + 0);            // 256 KB bf16 h
    short* hb1 = (short*)(ws + 262144);       // 256 KB
    float* hf0 = (float*)(ws + 524288);       // 512 KB f32 h master
    float* hf1 = (float*)(ws + 1048576);      // 512 KB
    float* genc = (float*)(ws + 1572864);     // 192 KB
    float* gdec = (float*)(ws + 1769472);     // 192 KB
    unsigned* bar = (unsigned*)(ws + 1966080);// 1 KB barrier state
    (void)in_sizes; (void)n_in; (void)out_size; (void)ws_size;

    // zero: h0 buffers, barrier state, output accumulators (covers G tables too; overwritten next)
    hipMemsetAsync(d_ws, 0, 1967104, stream);
    hipMemsetAsync(d_out, 0, 513 * sizeof(float), stream);

    build_tables<<<dim3(384), dim3(256), 0, stream>>>(emb_enc, wih_e, bih_e,
                                                      emb_dec, wih_d, bih_d, genc, gdec);

    KParams kp{tokens, whh_e, bhh_e, whh_d, bhh_d, wout, bout,
               genc, gdec, hb0, hb1, hf0, hf1, bar, (float*)d_out};
    void* args[] = {&kp};
    hipLaunchCooperativeKernel((void*)gru_seq, dim3(256), dim3(256), args, 0, stream);
}

// Round 4
// 4082.762 us; speedup vs baseline: 9.6613x; 9.6613x over previous
//
#include <hip/hip_runtime.h>
#include <hip/hip_bf16.h>

#define HID 512
#define NSEQ 256
#define SLEN 512
#define VOC 32
#define SOS_TOK 0

typedef __attribute__((ext_vector_type(8))) short short8;
typedef __attribute__((ext_vector_type(4))) float f32x4;

static __device__ __forceinline__ short f2bf(float f) {
    unsigned u = __builtin_bit_cast(unsigned, f);
    unsigned r = (u + 0x7fffu + ((u >> 16) & 1u)) >> 16;
    return (short)r;
}

// ---------------- G tables: G = (relu?)(emb) @ W_ih^T + b_ih, [32 tok][1536] ----------------
__global__ void build_tables(const float* __restrict__ emb_enc, const float* __restrict__ wih_e,
                             const float* __restrict__ bih_e,
                             const float* __restrict__ emb_dec, const float* __restrict__ wih_d,
                             const float* __restrict__ bih_d,
                             float* __restrict__ genc, float* __restrict__ gdec) {
    int gid = blockIdx.x * blockDim.x + threadIdx.x;
    if (gid >= 2 * 32 * 1536) return;
    int which = gid >= 49152;
    int r = gid - which * 49152;
    int tok = r / 1536, n = r - tok * 1536;
    const float4* e = (const float4*)((which ? emb_dec : emb_enc) + tok * HID);
    const float4* w = (const float4*)((which ? wih_d : wih_e) + n * HID);
    float s = 0.f;
#pragma unroll 4
    for (int k = 0; k < 128; ++k) {
        float4 ev = e[k], wv = w[k];
        if (which) {
            ev.x = fmaxf(ev.x, 0.f); ev.y = fmaxf(ev.y, 0.f);
            ev.z = fmaxf(ev.z, 0.f); ev.w = fmaxf(ev.w, 0.f);
        }
        s += ev.x * wv.x + ev.y * wv.y + ev.z * wv.z + ev.w * wv.w;
    }
    s += which ? bih_d[n] : bih_e[n];
    (which ? gdec : genc)[r] = s;
}

struct KParams {
    const int* tokens;
    const float* whh_e; const float* bhh_e;
    const float* whh_d; const float* bhh_d;
    const float* wout;  const float* bout;
    const float* genc;  const float* gdec;
    unsigned short* hb0; unsigned short* hb1; // bf16 h ping-pong (MALL-coherent access only)
    unsigned* bar;                            // 8 groups x monotonic counter @ mi*32
    float* out;                               // [512] embeds + [1] loss
};

// MALL-coherent 16B load (bypasses L1/L2 so cross-XCD stores are visible without fences)
static __device__ __forceinline__ short8 coh_load16(const unsigned short* addr) {
    short8 v;
    asm volatile("global_load_dwordx4 %0, %1, off sc0 sc1"
                 : "=&v"(v) : "v"(addr) : "memory");
    return v;
}

__global__ __launch_bounds__(256, 1) void gru_seq(KParams p) {
    const int tid = threadIdx.x;
    const int lane = tid & 63;
    const int wave = tid >> 6;
    const int mf = wave >> 1;       // row sub-tile 0..1
    const int kh = wave & 1;        // K half 0..1
    const int mi = blockIdx.x >> 5; // batch group 0..7
    const int hj = blockIdx.x & 31; // hidden col block 0..31

    __shared__ __align__(16) short Wp[48 * 512];    // swizzled [n][k] bf16
    __shared__ __align__(16) short WoutL[32 * 512]; // swizzled [v][k] bf16
    __shared__ float GencL[32 * 48];
    __shared__ float GdecL[32 * 48];
    __shared__ float bhhL[48];
    __shared__ float boutL[32];
    __shared__ float redbuf[2][3][16][16];
    __shared__ float hredbuf[2][2][16][16];
    __shared__ float logitsL[32][33];
    __shared__ int tokL[32];

    // ---------------- setup ----------------
    for (int i = tid; i < 32 * 48; i += 256) {
        int tok = i / 48, c = i - tok * 48;
        int gcol = (c >> 4) * HID + hj * 16 + (c & 15);
        GencL[i] = p.genc[tok * 1536 + gcol];
        GdecL[i] = p.gdec[tok * 1536 + gcol];
    }
    if (hj == 0) {
        for (int i = tid; i < 32 * 512; i += 256) {
            int v = i >> 9, k = i & 511;
            WoutL[v * 512 + (((k >> 3) ^ (v & 7)) << 3) + (k & 7)] = f2bf(p.wout[v * 512 + k]);
        }
        if (tid < 32) boutL[tid] = p.bout[tid];
    }
    auto load_panel = [&](const float* whh, const float* bhh) {
        for (int i = tid; i < 48 * 512; i += 256) {
            int rowl = i >> 9, k = i & 511;
            int nrow = (rowl >> 4) * HID + hj * 16 + (rowl & 15);
            Wp[rowl * 512 + (((k >> 3) ^ (rowl & 7)) << 3) + (k & 7)] = f2bf(whh[nrow * HID + k]);
        }
        if (tid < 48) bhhL[tid] = bhh[(tid >> 4) * HID + hj * 16 + (tid & 15)];
    };
    load_panel(p.whh_e, p.bhh_e);
    __syncthreads();

    float loss_acc = 0.f;
    float hreg[4] = {0.f, 0.f, 0.f, 0.f}; // f32 master h (meaningful in kh==0 waves)
    const int arow_l = mf * 16 + (lane & 15); // local row 0..31
    const int row_g = mi * 32 + arow_l;
    const int koff = (lane >> 4) * 8;

    unsigned* cnt = p.bar + mi * 32;
    unsigned bar_target = 0;

    for (int phase = 0; phase < 2; ++phase) {
        const float* G = phase ? GdecL : GencL;
        const int nsteps = phase ? (SLEN + 1) : SLEN;
        for (int t = 0; t < nsteps; ++t) {
            const int gstep = phase * SLEN + t;
            const unsigned short* hc = (gstep & 1) ? p.hb1 : p.hb0;
            unsigned short* hn = (gstep & 1) ? p.hb0 : p.hb1;
            const bool do_gru = (t < SLEN);
            const bool do_head = (phase == 1) && (t >= 1) && (hj == 0);

            int my_tgt = 0;
            if (tid < 32) {
                int rg = mi * 32 + tid;
                int tk = SOS_TOK;
                if (phase == 0) tk = p.tokens[rg * SLEN + t];
                else if (t >= 1 && t < SLEN) tk = p.tokens[rg * SLEN + t - 1];
                tokL[tid] = tk;
                if (do_head) my_tgt = p.tokens[rg * SLEN + (t - 1)];
            }

            short8 a[8];
            if (do_gru || do_head) {
                const unsigned short* ab = hc + row_g * HID + kh * 256 + koff;
#pragma unroll
                for (int kk = 0; kk < 8; ++kk) a[kk] = coh_load16(ab + kk * 32);
                asm volatile("s_waitcnt vmcnt(0)" ::: "memory");
                __builtin_amdgcn_sched_barrier(0);
            }

            f32x4 acc0 = {0.f, 0.f, 0.f, 0.f};
            f32x4 acc1 = {0.f, 0.f, 0.f, 0.f};
            f32x4 acc2 = {0.f, 0.f, 0.f, 0.f};
            if (do_gru) {
#pragma unroll
                for (int kk = 0; kk < 8; ++kk) {
                    const int ch = (kh * 8 + kk) * 4 + (lane >> 4); // 16B chunk idx 0..63
                    {
                        const int br = lane & 15;
                        short8 b = *(const short8*)(Wp + br * 512 + ((ch ^ (br & 7)) << 3));
                        acc0 = __builtin_amdgcn_mfma_f32_16x16x32_bf16(a[kk], b, acc0, 0, 0, 0);
                    }
                    {
                        const int br = 16 + (lane & 15);
                        short8 b = *(const short8*)(Wp + br * 512 + ((ch ^ (br & 7)) << 3));
                        acc1 = __builtin_amdgcn_mfma_f32_16x16x32_bf16(a[kk], b, acc1, 0, 0, 0);
                    }
                    {
                        const int br = 32 + (lane & 15);
                        short8 b = *(const short8*)(Wp + br * 512 + ((ch ^ (br & 7)) << 3));
                        acc2 = __builtin_amdgcn_mfma_f32_16x16x32_bf16(a[kk], b, acc2, 0, 0, 0);
                    }
                }
            }
            f32x4 ha0 = {0.f, 0.f, 0.f, 0.f};
            f32x4 ha1 = {0.f, 0.f, 0.f, 0.f};
            if (do_head) {
#pragma unroll
                for (int kk = 0; kk < 8; ++kk) {
                    const int ch = (kh * 8 + kk) * 4 + (lane >> 4);
                    {
                        const int br = lane & 15;
                        short8 b = *(const short8*)(WoutL + br * 512 + ((ch ^ (br & 7)) << 3));
                        ha0 = __builtin_amdgcn_mfma_f32_16x16x32_bf16(a[kk], b, ha0, 0, 0, 0);
                    }
                    {
                        const int br = 16 + (lane & 15);
                        short8 b = *(const short8*)(WoutL + br * 512 + ((ch ^ (br & 7)) << 3));
                        ha1 = __builtin_amdgcn_mfma_f32_16x16x32_bf16(a[kk], b, ha1, 0, 0, 0);
                    }
                }
            }

            if (kh == 1) {
                if (do_gru) {
#pragma unroll
                    for (int j = 0; j < 4; ++j) {
                        int r = (lane >> 4) * 4 + j, c = lane & 15;
                        redbuf[mf][0][r][c] = acc0[j];
                        redbuf[mf][1][r][c] = acc1[j];
                        redbuf[mf][2][r][c] = acc2[j];
                    }
                }
                if (do_head) {
#pragma unroll
                    for (int j = 0; j < 4; ++j) {
                        int r = (lane >> 4) * 4 + j, c = lane & 15;
                        hredbuf[mf][0][r][c] = ha0[j];
                        hredbuf[mf][1][r][c] = ha1[j];
                    }
                }
            }
            __syncthreads();
            if (kh == 0) {
                if (do_gru) {
#pragma unroll
                    for (int j = 0; j < 4; ++j) {
                        int r = (lane >> 4) * 4 + j;
                        int c = lane & 15;
                        int rl = mf * 16 + r;
                        float ghr = acc0[j] + redbuf[mf][0][r][c] + bhhL[c];
                        float ghz = acc1[j] + redbuf[mf][1][r][c] + bhhL[16 + c];
                        float ghn = acc2[j] + redbuf[mf][2][r][c] + bhhL[32 + c];
                        int tk = tokL[rl];
                        float gxr = G[tk * 48 + c];
                        float gxz = G[tk * 48 + 16 + c];
                        float gxn = G[tk * 48 + 32 + c];
                        float rg_ = 1.f / (1.f + __expf(-(gxr + ghr)));
                        float zg_ = 1.f / (1.f + __expf(-(gxz + ghz)));
                        float pre = gxn + rg_ * ghn;
                        float e2 = __expf(2.f * pre);
                        float ng_ = 1.f - 2.f / (e2 + 1.f);
                        float hnew = (1.f - zg_) * ng_ + zg_ * hreg[j];
                        hreg[j] = hnew;
                        int rgl = mi * 32 + rl;
                        // coherent (write-through) 2B store — visible at MALL without fences
                        __hip_atomic_store(hn + rgl * HID + hj * 16 + c,
                                           (unsigned short)f2bf(hnew),
                                           __ATOMIC_RELAXED, __HIP_MEMORY_SCOPE_AGENT);
                    }
                    if (phase == 0 && t == SLEN - 1) {
                        float s = hreg[0] + hreg[1] + hreg[2] + hreg[3];
                        s += __shfl_xor(s, 16);
                        s += __shfl_xor(s, 32);
                        if (lane < 16) atomicAdd(p.out + hj * 16 + lane, s * (1.f / 256.f));
                    }
                }
                if (do_head) {
#pragma unroll
                    for (int j = 0; j < 4; ++j) {
                        int r = (lane >> 4) * 4 + j, c = lane & 15;
                        logitsL[mf * 16 + r][c] = ha0[j] + hredbuf[mf][0][r][c] + boutL[c];
                        logitsL[mf * 16 + r][16 + c] = ha1[j] + hredbuf[mf][1][r][c] + boutL[16 + c];
                    }
                }
            }
            if (do_head) {
                __syncthreads();
                if (tid < 32) {
                    float mx = -1e30f;
#pragma unroll
                    for (int v = 0; v < VOC; ++v) mx = fmaxf(mx, logitsL[tid][v]);
                    float se = 0.f;
#pragma unroll
                    for (int v = 0; v < VOC; ++v) se += __expf(logitsL[tid][v] - mx);
                    loss_acc += mx + __logf(se) - logitsL[tid][my_tgt];
                }
            }

            // ---- fence-free group barrier: monotonic counter, one arrival per block/step ----
            bar_target += 32;
            __syncthreads(); // drains each wave's h stores (vmcnt 0) before arrival
            if (tid == 0) {
                atomicAdd(cnt, 1u); // device-scope RMW at coherence point (m20)
                while (__hip_atomic_load(cnt, __ATOMIC_RELAXED, __HIP_MEMORY_SCOPE_AGENT) < bar_target)
                    __builtin_amdgcn_s_sleep(1);
            }
            __syncthreads();
        }
        if (phase == 0) {
            load_panel(p.whh_d, p.bhh_d);
            __syncthreads();
        }
    }

    if (hj == 0 && wave == 0) {
        float v = loss_acc; // nonzero only in lanes 0..31
#pragma unroll
        for (int off = 32; off >= 1; off >>= 1) v += __shfl_xor(v, off);
        if (lane == 0) atomicAdd(p.out + HID, v * (1.f / (256.f * 512.f)));
    }
}

extern "C" void kernel_launch(void* const* d_in, const int* in_sizes, int n_in,
                              void* d_out, int out_size, void* d_ws, size_t ws_size,
                              hipStream_t stream) {
    const int* tokens = (const int*)d_in[0];
    const float* emb_enc = (const float*)d_in[1];
    const float* wih_e = (const float*)d_in[2];
    const float* whh_e = (const float*)d_in[3];
    const float* bih_e = (const float*)d_in[4];
    const float* bhh_e = (const float*)d_in[5];
    const float* emb_dec = (const float*)d_in[6];
    const float* wih_d = (const float*)d_in[7];
    const float* whh_d = (const float*)d_in[8];
    const float* bih_d = (const float*)d_in[9];
    const float* bhh_d = (const float*)d_in[10];
    const float* wout = (const float*)d_in[11];
    const float* bout = (const float*)d_in[12];

    char* ws = (char*)d_ws;
    unsigned short* hb0 = (unsigned short*)(ws + 0);       // 256 KB bf16 h
    unsigned short* hb1 = (unsigned short*)(ws + 262144);  // 256 KB
    float* genc = (float*)(ws + 524288);                   // 192 KB
    float* gdec = (float*)(ws + 720896);                   // 192 KB
    unsigned* bar = (unsigned*)(ws + 917504);              // barrier counters
    (void)in_sizes; (void)n_in; (void)out_size; (void)ws_size;

    // zero: h0 buffers, G tables (overwritten), barrier counters, output accumulators
    hipMemsetAsync(d_ws, 0, 918528, stream);
    hipMemsetAsync(d_out, 0, 513 * sizeof(float), stream);

    build_tables<<<dim3(384), dim3(256), 0, stream>>>(emb_enc, wih_e, bih_e,
                                                      emb_dec, wih_d, bih_d, genc, gdec);

    KParams kp{tokens, whh_e, bhh_e, whh_d, bhh_d, wout, bout,
               genc, gdec, hb0, hb1, bar, (float*)d_out};
    void* args[] = {&kp};
    hipLaunchCooperativeKernel((void*)gru_seq, dim3(256), dim3(256), args, 0, stream);
}